// Round 8
// baseline (687.954 us; speedup 1.0000x reference)
//
#include <hip/hip_runtime.h>

// ---------------------------------------------------------------------------
// 6-layer GCN. Layer l: y = b + D^-1/2(A+I)D^-1/2 h ; x_next = lrelu(y)
// R7: R5 chain + (a) lrelu folded into agg epilogue (stores activated y),
//     (b) scalar-broadcast GEMM: row made wave-uniform via readfirstlane so
//     x[row,k] compiles to SGPR loads; inner loop = pure v_fma against wreg.
// d_ws layout: rowptr[N+1] | dinv[N] | ssrc[E] | bufA[64N] | bufB[64N]
// Build temps alias into bufA (released before layer 0 writes bufA).
// ---------------------------------------------------------------------------

// --- pass 1: coarse histogram of dst>>7 into NB buckets ---------------------
__global__ __launch_bounds__(256) void bucket_hist(const int* __restrict__ dst,
                                                   int* __restrict__ ghist,
                                                   int E, int NB) {
    __shared__ int h[1024];
    for (int i = threadIdx.x; i < NB; i += 256) h[i] = 0;
    __syncthreads();
    int i = blockIdx.x * blockDim.x + threadIdx.x;
    int stride = gridDim.x * blockDim.x;
    for (; i < E; i += stride) atomicAdd(&h[dst[i] >> 7], 1);
    __syncthreads();
    for (int j = threadIdx.x; j < NB; j += 256) {
        int c = h[j];
        if (c) atomicAdd(&ghist[j], c);
    }
}

// --- pass 2: exclusive scan of bucket counts (single block, 1024 thr) -------
__global__ void bucket_scan(const int* __restrict__ ghist, int* __restrict__ base,
                            int* __restrict__ cursor, int NB, int E) {
    int tid = threadIdx.x, lane = tid & 63, wid = tid >> 6;
    int v = (tid < NB) ? ghist[tid] : 0;
    int incl = v;
#pragma unroll
    for (int off = 1; off < 64; off <<= 1) {
        int t = __shfl_up(incl, off);
        if (lane >= off) incl += t;
    }
    __shared__ int ws[16];
    if (lane == 63) ws[wid] = incl;
    __syncthreads();
    if (tid == 0) {
        int run = 0;
        for (int i = 0; i < 16; ++i) { int t = ws[i]; ws[i] = run; run += t; }
    }
    __syncthreads();
    int excl = ws[wid] + incl - v;
    if (tid < NB) { base[tid] = excl; cursor[tid] = excl; }
    if (tid == 0) base[NB] = E;
}

// --- pass 3: scatter edges into bucket-sorted (bsrc, bdl) -------------------
__global__ __launch_bounds__(256) void bucket_scatter(
    const int* __restrict__ src, const int* __restrict__ dst,
    int* __restrict__ cursor, int* __restrict__ bsrc,
    unsigned char* __restrict__ bdl, int E, int NB) {
    __shared__ int h[1024];
    __shared__ int rb[1024];
    const int CH = 4096;
    for (int c0 = blockIdx.x * CH; c0 < E; c0 += gridDim.x * CH) {
        int cend = c0 + CH < E ? c0 + CH : E;
        for (int j = threadIdx.x; j < NB; j += 256) h[j] = 0;
        __syncthreads();
        for (int i = c0 + threadIdx.x; i < cend; i += 256)
            atomicAdd(&h[dst[i] >> 7], 1);
        __syncthreads();
        for (int j = threadIdx.x; j < NB; j += 256) {
            int c = h[j];
            rb[j] = c ? atomicAdd(&cursor[j], c) : 0;
            h[j] = 0;
        }
        __syncthreads();
        for (int i = c0 + threadIdx.x; i < cend; i += 256) {
            int d = dst[i];
            int b = d >> 7;
            int p = rb[b] + atomicAdd(&h[b], 1);
            bsrc[p] = src[i];
            bdl[p] = (unsigned char)(d & 127);
        }
        __syncthreads();
    }
}

// --- pass 4: per-bucket CSR finalize: rowptr, dinv, ssrc --------------------
__global__ __launch_bounds__(256) void bucket_finalize(
    const int* __restrict__ base, const int* __restrict__ bsrc,
    const unsigned char* __restrict__ bdl, int* __restrict__ rowptr,
    int* __restrict__ ssrc, float* __restrict__ dinv, int N, int NB, int E) {
    __shared__ int cnt[128];
    __shared__ int cur[128];
    __shared__ int w0sum;
    const int tid = threadIdx.x;
    const int lane = tid & 63;
    for (int b = blockIdx.x; b < NB; b += gridDim.x) {
        const int s = base[b], e = base[b + 1];
        const int d0 = b << 7;
        const int w = (N - d0 < 128) ? (N - d0) : 128;
        if (tid < 128) cnt[tid] = 0;
        __syncthreads();
        for (int i = s + tid; i < e; i += 256) atomicAdd(&cnt[bdl[i]], 1);
        __syncthreads();
        int v = (tid < 128) ? cnt[tid] : 0;
        int incl = v;
#pragma unroll
        for (int off = 1; off < 64; off <<= 1) {
            int t = __shfl_up(incl, off);
            if (lane >= off) incl += t;
        }
        if (tid == 63) w0sum = incl;
        __syncthreads();
        int excl = incl - v + ((tid >= 64 && tid < 128) ? w0sum : 0);
        if (tid < 128) cur[tid] = s + excl;
        if (tid < w) {
            rowptr[d0 + tid] = s + excl;
            dinv[d0 + tid] = rsqrtf((float)(v + 1));   // +1 self loop
        }
        __syncthreads();
        for (int i = s + tid; i < e; i += 256) {
            int p = atomicAdd(&cur[bdl[i]], 1);
            ssrc[p] = bsrc[i];
        }
        __syncthreads();
    }
    if (blockIdx.x == 0 && tid == 0) rowptr[N] = E;
}

// --- scalar-broadcast dense transform + dinv pre-scale:
//   hs[row,l] = dinv[row] * sum_k in[row,k] * W[k,l]
// `in` is PRE-ACTIVATED (lrelu already applied by producer) or raw (layer 0).
// Row index is made wave-uniform (readfirstlane) so in[row,k] becomes scalar
// (SGPR) loads; the inner loop is pure v_fma against per-lane wreg.
template <int K>
__global__ __launch_bounds__(256) void gemm_hs(
    const float* __restrict__ in, const float* __restrict__ W,
    const float* __restrict__ dinv, float* __restrict__ hs, int n) {
    const int lane = threadIdx.x & 63;
    const int gw = blockIdx.x * (blockDim.x >> 6) + (threadIdx.x >> 6);
    const int nw = gridDim.x * (blockDim.x >> 6);

    float wreg[K];
#pragma unroll
    for (int k = 0; k < K; ++k) wreg[k] = W[k * 64 + lane];

    for (int row = gw; row < n; row += nw) {
        const int r = __builtin_amdgcn_readfirstlane(row);
        const float4* __restrict__ xr = (const float4*)(in + (size_t)r * K);
        float a0 = 0.f, a1 = 0.f, a2 = 0.f, a3 = 0.f;
#pragma unroll
        for (int k4 = 0; k4 < K / 4; ++k4) {
            float4 xv = xr[k4];
            a0 = fmaf(xv.x, wreg[4 * k4 + 0], a0);
            a1 = fmaf(xv.y, wreg[4 * k4 + 1], a1);
            a2 = fmaf(xv.z, wreg[4 * k4 + 2], a2);
            a3 = fmaf(xv.w, wreg[4 * k4 + 3], a3);
        }
        float acc = (a0 + a1) + (a2 + a3);
        hs[(size_t)r * 64 + lane] = dinv[r] * acc;
    }
}

// --- aggregation: wave = dst row (edge-balanced contiguous ranges),
//     lane = feature; stores x_next = lrelu(b + dinv[d]*(self + gather-sum)) -
__global__ __launch_bounds__(256) void csr_agg_act(
    const float* __restrict__ hs, const int* __restrict__ rowptr,
    const int* __restrict__ ssrc, const float* __restrict__ dinv,
    const float* __restrict__ b, float* __restrict__ xact,
    int N, int E, int nwaves) {
    const int lane = threadIdx.x & 63;
    const int w = blockIdx.x * (blockDim.x >> 6) + (threadIdx.x >> 6);
    if (w >= nwaves) return;
    const float bl = b[lane];

    // first row r with rowptr[r] >= t   (r in [0, N])
    auto lb = [&](long long t) {
        int lo = 0, hi = N;
        while (lo < hi) {
            int m = (lo + hi) >> 1;
            if ((long long)rowptr[m] < t) lo = m + 1; else hi = m;
        }
        return lo;
    };
    const long long q0 = (long long)w * E / nwaves;
    const long long q1 = (long long)(w + 1) * E / nwaves;
    int r0 = lb(q0);
    int r1 = (w == nwaves - 1) ? N : lb(q1);

    for (int d = r0; d < r1; ++d) {
        int e = __builtin_amdgcn_readfirstlane(rowptr[d]);
        const int end = __builtin_amdgcn_readfirstlane(rowptr[d + 1]);
        float acc0 = hs[(size_t)d * 64 + lane];   // self loop (pre-scaled)
        float acc1 = 0.f;
        for (; e + 8 <= end; e += 8) {
            int s0 = __builtin_nontemporal_load(ssrc + e + 0);
            int s1 = __builtin_nontemporal_load(ssrc + e + 1);
            int s2 = __builtin_nontemporal_load(ssrc + e + 2);
            int s3 = __builtin_nontemporal_load(ssrc + e + 3);
            int s4 = __builtin_nontemporal_load(ssrc + e + 4);
            int s5 = __builtin_nontemporal_load(ssrc + e + 5);
            int s6 = __builtin_nontemporal_load(ssrc + e + 6);
            int s7 = __builtin_nontemporal_load(ssrc + e + 7);
            float v0 = hs[(size_t)s0 * 64 + lane];
            float v1 = hs[(size_t)s1 * 64 + lane];
            float v2 = hs[(size_t)s2 * 64 + lane];
            float v3 = hs[(size_t)s3 * 64 + lane];
            float v4 = hs[(size_t)s4 * 64 + lane];
            float v5 = hs[(size_t)s5 * 64 + lane];
            float v6 = hs[(size_t)s6 * 64 + lane];
            float v7 = hs[(size_t)s7 * 64 + lane];
            acc0 += v0 + v2;
            acc1 += v1 + v3;
            acc0 += v4 + v6;
            acc1 += v5 + v7;
        }
        for (; e < end; ++e) {
            int s = __builtin_nontemporal_load(ssrc + e);
            acc0 += hs[(size_t)s * 64 + lane];
        }
        float y = fmaf(dinv[d], acc0 + acc1, bl);
        y = y >= 0.f ? y : 0.2f * y;              // lrelu folded here
        xact[(size_t)d * 64 + lane] = y;
    }
}

// --- final layer gemm: pre-activated x -> W5[64,4] -> dinv scale ------------
__global__ __launch_bounds__(256) void gemm4_hs(
    const float* __restrict__ xact, const float* __restrict__ W,  // [64,4]
    const float* __restrict__ dinv, float* __restrict__ hs4, int n) {
    int i = blockIdx.x * blockDim.x + threadIdx.x;
    int stride = gridDim.x * blockDim.x;
    for (; i < n; i += stride) {
        const float4* xr = (const float4*)(xact + (size_t)i * 64);
        float a0 = 0.f, a1 = 0.f, a2 = 0.f, a3 = 0.f;
#pragma unroll
        for (int k4 = 0; k4 < 16; ++k4) {
            float4 xv = xr[k4];
            int k = k4 * 4;
            a0 = fmaf(xv.x, W[(k + 0) * 4 + 0], a0); a1 = fmaf(xv.x, W[(k + 0) * 4 + 1], a1);
            a2 = fmaf(xv.x, W[(k + 0) * 4 + 2], a2); a3 = fmaf(xv.x, W[(k + 0) * 4 + 3], a3);
            a0 = fmaf(xv.y, W[(k + 1) * 4 + 0], a0); a1 = fmaf(xv.y, W[(k + 1) * 4 + 1], a1);
            a2 = fmaf(xv.y, W[(k + 1) * 4 + 2], a2); a3 = fmaf(xv.y, W[(k + 1) * 4 + 3], a3);
            a0 = fmaf(xv.z, W[(k + 2) * 4 + 0], a0); a1 = fmaf(xv.z, W[(k + 2) * 4 + 1], a1);
            a2 = fmaf(xv.z, W[(k + 2) * 4 + 2], a2); a3 = fmaf(xv.z, W[(k + 2) * 4 + 3], a3);
            a0 = fmaf(xv.w, W[(k + 3) * 4 + 0], a0); a1 = fmaf(xv.w, W[(k + 3) * 4 + 1], a1);
            a2 = fmaf(xv.w, W[(k + 3) * 4 + 2], a2); a3 = fmaf(xv.w, W[(k + 3) * 4 + 3], a3);
        }
        float di = dinv[i];
        ((float4*)hs4)[i] = make_float4(di * a0, di * a1, di * a2, di * a3);
    }
}

// --- final aggregation over pre-scaled hs4: out = b + dinv[d]*(self + sum) --
__global__ __launch_bounds__(256) void csr_agg4(
    const float* __restrict__ hs4, const int* __restrict__ rowptr,
    const int* __restrict__ ssrc, const float* __restrict__ dinv,
    const float* __restrict__ b, float* __restrict__ out, int n) {
    int i = blockIdx.x * blockDim.x + threadIdx.x;
    int stride = gridDim.x * blockDim.x;
    float b0 = b[0], b1 = b[1], b2 = b[2], b3 = b[3];
    for (; i < n; i += stride) {
        float4 hv = ((const float4*)hs4)[i];
        float a0 = hv.x, a1 = hv.y, a2 = hv.z, a3 = hv.w;   // self loop
        int e = rowptr[i], end = rowptr[i + 1];
        for (; e < end; ++e) {
            int s = ssrc[e];
            float4 v = ((const float4*)hs4)[s];
            a0 += v.x; a1 += v.y; a2 += v.z; a3 += v.w;
        }
        float di = dinv[i];
        ((float4*)out)[i] = make_float4(fmaf(di, a0, b0), fmaf(di, a1, b1),
                                        fmaf(di, a2, b2), fmaf(di, a3, b3));
    }
}

static inline size_t al64(size_t x) { return (x + 63) & ~(size_t)63; }

extern "C" void kernel_launch(void* const* d_in, const int* in_sizes, int n_in,
                              void* d_out, int out_size, void* d_ws, size_t ws_size,
                              hipStream_t stream) {
    const float* x  = (const float*)d_in[0];
    const int* ei   = (const int*)d_in[1];
    const float* W0 = (const float*)d_in[2];
    const float* b0 = (const float*)d_in[3];
    const float* W1 = (const float*)d_in[4];
    const float* b1 = (const float*)d_in[5];
    const float* W2 = (const float*)d_in[6];
    const float* b2 = (const float*)d_in[7];
    const float* W3 = (const float*)d_in[8];
    const float* b3 = (const float*)d_in[9];
    const float* W4 = (const float*)d_in[10];
    const float* b4 = (const float*)d_in[11];
    const float* W5 = (const float*)d_in[12];
    const float* b5 = (const float*)d_in[13];

    const int N = in_sizes[0] / 128;
    const int E = in_sizes[1] / 2;
    const int* src  = ei;       // edge_index[0] = message sources
    const int* dstp = ei + E;   // edge_index[1] = aggregation targets
    const int NB = (N + 127) >> 7;   // dst buckets of 128 ids (NB <= 1024)

    float* ws = (float*)d_ws;
    size_t off = 0;
    int*   rowptr = (int*)(ws + off);   off += al64((size_t)N + 1);
    float* dinv   = ws + off;           off += al64((size_t)N);
    int*   ssrc   = (int*)(ws + off);   off += al64((size_t)E);
    float* bufA   = ws + off;           off += (size_t)64 * N;
    float* bufB   = ws + off;

    // build temps alias into bufA (released before layer 0 writes bufA)
    int* ghist = (int*)bufA;                       // [1024]
    int* bbase = ghist + 1024;                     // [NB+1]
    int* bcur  = bbase + 1088;                     // [NB]
    int* bsrc  = (int*)(bufA + 4096);              // [E]
    unsigned char* bdl = (unsigned char*)(bsrc + E);  // [E]

    // ---- graph build (bucketed counting sort) ----
    hipMemsetAsync(ghist, 0, 1024 * sizeof(int), stream);
    bucket_hist<<<391, 256, 0, stream>>>(dstp, ghist, E, NB);
    bucket_scan<<<1, 1024, 0, stream>>>(ghist, bbase, bcur, NB, E);
    bucket_scatter<<<391, 256, 0, stream>>>(src, dstp, bcur, bsrc, bdl, E, NB);
    bucket_finalize<<<NB, 256, 0, stream>>>(bbase, bsrc, bdl, rowptr, ssrc, dinv, N, NB, E);

    const int AGG_BLOCKS = 2048;
    const int NWAVES = AGG_BLOCKS * 4;

    // ---- layer 0: x[N,128] -> hs0 ----
    gemm_hs<128><<<2048, 256, 0, stream>>>(x, W0, dinv, bufA, N);
    csr_agg_act<<<AGG_BLOCKS, 256, 0, stream>>>(bufA, rowptr, ssrc, dinv, b0, bufB, N, E, NWAVES);

    // ---- layers 1-4 (xact in bufB -> hs in bufA -> xact in bufB) ----
    const float* Ws[4] = {W1, W2, W3, W4};
    const float* bs[4] = {b1, b2, b3, b4};
    for (int l = 0; l < 4; ++l) {
        gemm_hs<64><<<2048, 256, 0, stream>>>(bufB, Ws[l], dinv, bufA, N);
        csr_agg_act<<<AGG_BLOCKS, 256, 0, stream>>>(bufA, rowptr, ssrc, dinv, bs[l], bufB, N, E, NWAVES);
    }

    // ---- layer 5: xact -> hs4[N,4] -> out ----
    gemm4_hs<<<1024, 256, 0, stream>>>(bufB, W5, dinv, bufA, N);
    csr_agg4<<<1024, 256, 0, stream>>>(bufA, rowptr, ssrc, dinv, b5, (float*)d_out, N);
}